// Round 1
// baseline (419.658 us; speedup 1.0000x reference)
//
#include <hip/hip_runtime.h>

using bf16x8 = __attribute__((ext_vector_type(8))) __bf16;
using f32x4  = __attribute__((ext_vector_type(4))) float;

#define C_ 64
#define S_ 128
#define H_ 2048
#define M_ 8192

__device__ __forceinline__ unsigned short f2bf(float f) {
  unsigned u = __float_as_uint(f);
  u = u + 0x7fffu + ((u >> 16) & 1u);   // RNE
  return (unsigned short)(u >> 16);
}
__device__ __forceinline__ float bf2f(unsigned short h) {
  return __uint_as_float(((unsigned)h) << 16);
}

// ---------------- split x into hi/lo bf16 ----------------
__global__ void k_split_x(const float* __restrict__ x,
                          unsigned short* __restrict__ xh,
                          unsigned short* __restrict__ xl) {
  int idx = blockIdx.x * 256 + threadIdx.x;          // n/4 = 4194304 threads
  float4 v = ((const float4*)x)[idx];
  float a[4] = {v.x, v.y, v.z, v.w};
  unsigned short h[4], l[4];
#pragma unroll
  for (int q = 0; q < 4; ++q) {
    h[q] = f2bf(a[q]);
    l[q] = f2bf(a[q] - bf2f(h[q]));
  }
  ((ushort4*)xh)[idx] = make_ushort4(h[0], h[1], h[2], h[3]);
  ((ushort4*)xl)[idx] = make_ushort4(l[0], l[1], l[2], l[3]);
}

// ------------- split + transpose W -> Wt[n][k] hi/lo -------------
__global__ void k_split_tw(const float* __restrict__ W,
                           unsigned short* __restrict__ Wth,
                           unsigned short* __restrict__ Wtl) {
  __shared__ float Ts[64][68];
  const int t = threadIdx.x;
  const int k0 = blockIdx.x * 64, n0 = blockIdx.y * 64;
#pragma unroll
  for (int p = 0; p < 4; ++p) {
    int idx = t + p * 256;
    int r = idx >> 4, c4 = (idx & 15) * 4;
    *(float4*)&Ts[r][c4] = *(const float4*)(W + (size_t)(k0 + r) * H_ + n0 + c4);
  }
  __syncthreads();
#pragma unroll
  for (int p = 0; p < 4; ++p) {
    int idx = t + p * 256;
    int rr = idx >> 4, cc = (idx & 15) * 4;   // rr = n-local, cc = k-local
    unsigned short h[4], l[4];
#pragma unroll
    for (int q = 0; q < 4; ++q) {
      float f = Ts[cc + q][rr];
      h[q] = f2bf(f);
      l[q] = f2bf(f - bf2f(h[q]));
    }
    size_t o = (size_t)(n0 + rr) * H_ + k0 + cc;
    *(ushort4*)(Wth + o) = make_ushort4(h[0], h[1], h[2], h[3]);
    *(ushort4*)(Wtl + o) = make_ushort4(l[0], l[1], l[2], l[3]);
  }
}

// ------- 3-term split-bf16 MFMA GEMM: E[M][N] = A[M][K] * Bt[N][K]^T -------
__global__ __launch_bounds__(256, 2) void k_gemm3(
    const unsigned short* __restrict__ Ah, const unsigned short* __restrict__ Al,
    const unsigned short* __restrict__ Bh, const unsigned short* __restrict__ Bl,
    float* __restrict__ E) {
  __shared__ unsigned short sAh[128][40], sAl[128][40], sBh[128][40], sBl[128][40];
  const int t = threadIdx.x;
  const int bn = blockIdx.x, bm = blockIdx.y;
  const int lane = t & 63, wid = t >> 6;
  const int wm = wid >> 1, wn = wid & 1;
  const int l16 = lane & 15, quad = lane >> 4;

  const int sr = t >> 2;            // 0..63
  const int sc = (t & 3) * 8;       // 0,8,16,24
  const unsigned short* pAh = Ah + (size_t)(bm * 128 + sr) * H_ + sc;
  const unsigned short* pAl = Al + (size_t)(bm * 128 + sr) * H_ + sc;
  const unsigned short* pBh = Bh + (size_t)(bn * 128 + sr) * H_ + sc;
  const unsigned short* pBl = Bl + (size_t)(bn * 128 + sr) * H_ + sc;
  const size_t r64 = (size_t)64 * H_;

  f32x4 acc[4][4];
#pragma unroll
  for (int i = 0; i < 4; ++i)
#pragma unroll
    for (int j = 0; j < 4; ++j) acc[i][j] = (f32x4)0.f;

  for (int k0 = 0; k0 < H_; k0 += 32) {
    __syncthreads();
    *(uint4*)&sAh[sr][sc]      = *(const uint4*)(pAh + k0);
    *(uint4*)&sAh[sr + 64][sc] = *(const uint4*)(pAh + r64 + k0);
    *(uint4*)&sAl[sr][sc]      = *(const uint4*)(pAl + k0);
    *(uint4*)&sAl[sr + 64][sc] = *(const uint4*)(pAl + r64 + k0);
    *(uint4*)&sBh[sr][sc]      = *(const uint4*)(pBh + k0);
    *(uint4*)&sBh[sr + 64][sc] = *(const uint4*)(pBh + r64 + k0);
    *(uint4*)&sBl[sr][sc]      = *(const uint4*)(pBl + k0);
    *(uint4*)&sBl[sr + 64][sc] = *(const uint4*)(pBl + r64 + k0);
    __syncthreads();

    bf16x8 ah[4], al[4], bh[4], bl[4];
#pragma unroll
    for (int i = 0; i < 4; ++i) {
      ah[i] = *(const bf16x8*)&sAh[wm * 64 + i * 16 + l16][quad * 8];
      al[i] = *(const bf16x8*)&sAl[wm * 64 + i * 16 + l16][quad * 8];
      bh[i] = *(const bf16x8*)&sBh[wn * 64 + i * 16 + l16][quad * 8];
      bl[i] = *(const bf16x8*)&sBl[wn * 64 + i * 16 + l16][quad * 8];
    }
#pragma unroll
    for (int i = 0; i < 4; ++i)
#pragma unroll
      for (int j = 0; j < 4; ++j) {
        acc[i][j] = __builtin_amdgcn_mfma_f32_16x16x32_bf16(ah[i], bh[j], acc[i][j], 0, 0, 0);
        acc[i][j] = __builtin_amdgcn_mfma_f32_16x16x32_bf16(ah[i], bl[j], acc[i][j], 0, 0, 0);
        acc[i][j] = __builtin_amdgcn_mfma_f32_16x16x32_bf16(al[i], bh[j], acc[i][j], 0, 0, 0);
      }
  }

#pragma unroll
  for (int i = 0; i < 4; ++i) {
    const int row0 = bm * 128 + wm * 64 + i * 16 + quad * 4;
#pragma unroll
    for (int j = 0; j < 4; ++j) {
      const int col = bn * 128 + wn * 64 + j * 16 + l16;
#pragma unroll
      for (int r = 0; r < 4; ++r)
        E[(size_t)(row0 + r) * H_ + col] = acc[i][j][r];
    }
  }
}

// ---------- fp32 Gram: G[c] += E[c,:,kchunk] * E[c,:,kchunk]^T ----------
__global__ __launch_bounds__(256, 2) void k_gram(const float* __restrict__ E,
                                                 float* __restrict__ G) {
  __shared__ float Es[128][68];
  const int t = threadIdx.x;
  const int kc = blockIdx.x;   // 0..7  (K chunk of 256)
  const int cc = blockIdx.y;   // 0..63 capsule
  const int ti = t >> 4, tj = t & 15;

  float acc[8][8];
#pragma unroll
  for (int i = 0; i < 8; ++i)
#pragma unroll
    for (int j = 0; j < 8; ++j) acc[i][j] = 0.f;

  const float* Ec = E + (size_t)cc * S_ * H_ + kc * 256;
  for (int sub = 0; sub < 4; ++sub) {
    const float* Esrc = Ec + sub * 64;
    __syncthreads();
#pragma unroll
    for (int p = 0; p < 8; ++p) {
      int idx = t + p * 256;
      int s = idx >> 4, c4 = (idx & 15) * 4;
      *(float4*)&Es[s][c4] = *(const float4*)(Esrc + (size_t)s * H_ + c4);
    }
    __syncthreads();
    for (int kk = 0; kk < 64; kk += 4) {
      float4 a4[8], b4[8];
#pragma unroll
      for (int i = 0; i < 8; ++i) a4[i] = *(const float4*)&Es[ti + i * 16][kk];
#pragma unroll
      for (int j = 0; j < 8; ++j) b4[j] = *(const float4*)&Es[tj + j * 16][kk];
#pragma unroll
      for (int i = 0; i < 8; ++i)
#pragma unroll
        for (int j = 0; j < 8; ++j) {
          acc[i][j] = fmaf(a4[i].x, b4[j].x, acc[i][j]);
          acc[i][j] = fmaf(a4[i].y, b4[j].y, acc[i][j]);
          acc[i][j] = fmaf(a4[i].z, b4[j].z, acc[i][j]);
          acc[i][j] = fmaf(a4[i].w, b4[j].w, acc[i][j]);
        }
    }
  }
  float* Gc = G + (size_t)cc * S_ * S_;
#pragma unroll
  for (int i = 0; i < 8; ++i)
#pragma unroll
    for (int j = 0; j < 8; ++j)
      atomicAdd(&Gc[(ti + i * 16) * S_ + (tj + j * 16)], acc[i][j]);
}

// ---------- per-capsule routing iterations on G only ----------
__global__ void k_iter(const float* __restrict__ G, float* __restrict__ wv) {
  const int c = blockIdx.x;
  const int s = threadIdx.x;   // 128 threads
  __shared__ float dsh[128];
  __shared__ float red[128];
  const float* Gc = G + (size_t)c * S_ * S_;
  float b = 0.f;
  for (int it = 0; it < 3; ++it) {
    red[s] = b; __syncthreads();
    for (int off = 64; off > 0; off >>= 1) {
      if (s < off) red[s] = fmaxf(red[s], red[s + off]);
      __syncthreads();
    }
    float mx = red[0]; __syncthreads();
    float ev = expf(b - mx);
    red[s] = ev; __syncthreads();
    for (int off = 64; off > 0; off >>= 1) {
      if (s < off) red[s] = red[s] + red[s + off];
      __syncthreads();
    }
    float Z = red[0]; __syncthreads();
    float d = ev / Z;
    dsh[s] = d; __syncthreads();
    float y = 0.f;   // y_s = (G d)_s, read G columns (symmetric) for coalescing
#pragma unroll 8
    for (int j = 0; j < S_; ++j) y = fmaf(Gc[j * S_ + s], dsh[j], y);
    red[s] = d * y; __syncthreads();
    for (int off = 64; off > 0; off >>= 1) {
      if (s < off) red[s] = red[s] + red[s + off];
      __syncthreads();
    }
    float sq = red[0]; __syncthreads();
    float coeff = sq / (1.f + sq) / sqrtf(sq + 1e-9f);
    if (it == 2) wv[c * S_ + s] = coeff * d;
    else b += coeff * y;
  }
}

// ---------- out[c,h] = sum_s wv[c,s] * E[c,s,h] ----------
__global__ void k_out(const float* __restrict__ E, const float* __restrict__ wv,
                      float* __restrict__ out) {
  const int c = blockIdx.y;
  const int h = blockIdx.x * 256 + threadIdx.x;
  __shared__ float wsh[128];
  if (threadIdx.x < 128) wsh[threadIdx.x] = wv[c * S_ + threadIdx.x];
  __syncthreads();
  const float* Ec = E + (size_t)c * S_ * H_ + h;
  float acc = 0.f;
#pragma unroll 8
  for (int s = 0; s < S_; ++s) acc = fmaf(wsh[s], Ec[(size_t)s * H_], acc);
  out[(size_t)c * H_ + h] = acc;
}

extern "C" void kernel_launch(void* const* d_in, const int* in_sizes, int n_in,
                              void* d_out, int out_size, void* d_ws, size_t ws_size,
                              hipStream_t stream) {
  (void)in_sizes; (void)n_in; (void)out_size; (void)ws_size;
  const float* x = (const float*)d_in[0];
  const float* W = (const float*)d_in[1];
  float* out = (float*)d_out;
  char* ws = (char*)d_ws;

  unsigned short* xh  = (unsigned short*)(ws);                 // 32 MiB
  unsigned short* xl  = (unsigned short*)(ws + 33554432);      // 32 MiB
  unsigned short* Wth = (unsigned short*)(ws + 67108864);      // 8 MiB
  unsigned short* Wtl = (unsigned short*)(ws + 75497472);      // 8 MiB
  float*          E   = (float*)(ws + 83886080);               // 64 MiB
  float*          G   = (float*)(ws + 150994944);              // 4 MiB
  float*          wv  = (float*)(ws + 155189248);              // 32 KiB

  hipMemsetAsync(G, 0, (size_t)C_ * S_ * S_ * sizeof(float), stream);
  k_split_x<<<dim3(16384), 256, 0, stream>>>(x, xh, xl);
  k_split_tw<<<dim3(32, 32), 256, 0, stream>>>(W, Wth, Wtl);
  k_gemm3<<<dim3(16, 64), 256, 0, stream>>>(xh, xl, Wth, Wtl, E);
  k_gram<<<dim3(8, 64), 256, 0, stream>>>(E, G);
  k_iter<<<dim3(64), 128, 0, stream>>>(G, wv);
  k_out<<<dim3(8, 64), 256, 0, stream>>>(E, wv, out);
}

// Round 2
// 405.474 us; speedup vs baseline: 1.0350x; 1.0350x over previous
//
#include <hip/hip_runtime.h>

using bf16x8 = __attribute__((ext_vector_type(8))) __bf16;
using f32x4  = __attribute__((ext_vector_type(4))) float;

#define C_ 64
#define S_ 128
#define H_ 2048
#define M_ 8192

__device__ __forceinline__ unsigned short f2bf(float f) {
  unsigned u = __float_as_uint(f);
  u = u + 0x7fffu + ((u >> 16) & 1u);   // RNE
  return (unsigned short)(u >> 16);
}
__device__ __forceinline__ float bf2f(unsigned short h) {
  return __uint_as_float(((unsigned)h) << 16);
}

// async global->LDS, 16 B per lane; LDS dest = uniform base + lane*16
__device__ __forceinline__ void glds16(const unsigned short* g, unsigned short* l) {
  __builtin_amdgcn_global_load_lds(
      (const __attribute__((address_space(1))) void*)g,
      (__attribute__((address_space(3))) void*)l, 16, 0, 0);
}

// ---------------- split x into hi/lo bf16 ----------------
__global__ void k_split_x(const float* __restrict__ x,
                          unsigned short* __restrict__ xh,
                          unsigned short* __restrict__ xl) {
  int idx = blockIdx.x * 256 + threadIdx.x;
  float4 v = ((const float4*)x)[idx];
  float a[4] = {v.x, v.y, v.z, v.w};
  unsigned short h[4], l[4];
#pragma unroll
  for (int q = 0; q < 4; ++q) {
    h[q] = f2bf(a[q]);
    l[q] = f2bf(a[q] - bf2f(h[q]));
  }
  ((ushort4*)xh)[idx] = make_ushort4(h[0], h[1], h[2], h[3]);
  ((ushort4*)xl)[idx] = make_ushort4(l[0], l[1], l[2], l[3]);
}

// ------------- split + transpose W -> Wt[n][k] hi/lo -------------
__global__ void k_split_tw(const float* __restrict__ W,
                           unsigned short* __restrict__ Wth,
                           unsigned short* __restrict__ Wtl) {
  __shared__ float Ts[64][68];
  const int t = threadIdx.x;
  const int k0 = blockIdx.x * 64, n0 = blockIdx.y * 64;
#pragma unroll
  for (int p = 0; p < 4; ++p) {
    int idx = t + p * 256;
    int r = idx >> 4, c4 = (idx & 15) * 4;
    *(float4*)&Ts[r][c4] = *(const float4*)(W + (size_t)(k0 + r) * H_ + n0 + c4);
  }
  __syncthreads();
#pragma unroll
  for (int p = 0; p < 4; ++p) {
    int idx = t + p * 256;
    int rr = idx >> 4, cc = (idx & 15) * 4;   // rr = n-local, cc = k-local
    unsigned short h[4], l[4];
#pragma unroll
    for (int q = 0; q < 4; ++q) {
      float f = Ts[cc + q][rr];
      h[q] = f2bf(f);
      l[q] = f2bf(f - bf2f(h[q]));
    }
    size_t o = (size_t)(n0 + rr) * H_ + k0 + cc;
    *(ushort4*)(Wth + o) = make_ushort4(h[0], h[1], h[2], h[3]);
    *(ushort4*)(Wtl + o) = make_ushort4(l[0], l[1], l[2], l[3]);
  }
}

// ------- 3-term split-bf16 MFMA GEMM: E[M][N] = A[M][K] * Bt[N][K]^T -------
// LDS layout per array: 128 rows x 32 ushorts (64 B), NO padding.
// 16B groups XOR-swizzled: stored group gs holds global group gs ^ ((row>>1)&3).
// -> staging writes (via global_load_lds, lane-contiguous) and fragment reads
//    both land 2 dwords/bank per quarter-wave: conflict-free.
__global__ __launch_bounds__(256, 4) void k_gemm3(
    const unsigned short* __restrict__ Ah, const unsigned short* __restrict__ Al,
    const unsigned short* __restrict__ Bh, const unsigned short* __restrict__ Bl,
    float* __restrict__ E) {
  __shared__ unsigned short sAh[128 * 32], sAl[128 * 32], sBh[128 * 32], sBl[128 * 32];
  const int t = threadIdx.x;
  const int bn = blockIdx.x, bm = blockIdx.y;
  const int lane = t & 63, wid = t >> 6;
  const int wm = wid >> 1, wn = wid & 1;
  const int l16 = lane & 15, quad = lane >> 4;

  // ---- staging geometry (per wave: 2 chunks of 16 rows per array) ----
  const int rl = lane >> 2;                    // row within 16-row chunk
  const int gg = (lane & 3) ^ ((rl >> 1) & 3); // global 16B-group for this lane's slot
  const int c0 = wid * 2, c1 = wid * 2 + 1;    // chunk ids 0..7
  const unsigned short* gAh0 = Ah + (size_t)(bm * 128 + c0 * 16 + rl) * H_ + gg * 8;
  const unsigned short* gAh1 = Ah + (size_t)(bm * 128 + c1 * 16 + rl) * H_ + gg * 8;
  const unsigned short* gAl0 = Al + (size_t)(bm * 128 + c0 * 16 + rl) * H_ + gg * 8;
  const unsigned short* gAl1 = Al + (size_t)(bm * 128 + c1 * 16 + rl) * H_ + gg * 8;
  const unsigned short* gBh0 = Bh + (size_t)(bn * 128 + c0 * 16 + rl) * H_ + gg * 8;
  const unsigned short* gBh1 = Bh + (size_t)(bn * 128 + c1 * 16 + rl) * H_ + gg * 8;
  const unsigned short* gBl0 = Bl + (size_t)(bn * 128 + c0 * 16 + rl) * H_ + gg * 8;
  const unsigned short* gBl1 = Bl + (size_t)(bn * 128 + c1 * 16 + rl) * H_ + gg * 8;
  unsigned short* lA0 = sAh + c0 * 512;  // chunk = 16 rows * 32 ushorts = 1024 B
  unsigned short* lA1 = sAh + c1 * 512;
  unsigned short* lAl0 = sAl + c0 * 512;
  unsigned short* lAl1 = sAl + c1 * 512;
  unsigned short* lB0 = sBh + c0 * 512;
  unsigned short* lB1 = sBh + c1 * 512;
  unsigned short* lBl0 = sBl + c0 * 512;
  unsigned short* lBl1 = sBl + c1 * 512;

  // ---- fragment read offsets (swizzle depends only on l16) ----
  const int swz = ((l16 >> 1) & 3);
  const int colq = ((quad ^ swz) * 8);

  f32x4 acc[4][4];
#pragma unroll
  for (int i = 0; i < 4; ++i)
#pragma unroll
    for (int j = 0; j < 4; ++j) acc[i][j] = (f32x4)0.f;

  for (int k0 = 0; k0 < H_; k0 += 32) {
    __syncthreads();
    glds16(gAh0 + k0, lA0);
    glds16(gAh1 + k0, lA1);
    glds16(gAl0 + k0, lAl0);
    glds16(gAl1 + k0, lAl1);
    glds16(gBh0 + k0, lB0);
    glds16(gBh1 + k0, lB1);
    glds16(gBl0 + k0, lBl0);
    glds16(gBl1 + k0, lBl1);
    __syncthreads();   // drains vmcnt (glds) before reads

    bf16x8 ah[4], al[4], bh[4], bl[4];
#pragma unroll
    for (int i = 0; i < 4; ++i) {
      const int ra = (wm * 64 + i * 16 + l16) * 32;
      const int rb = (wn * 64 + i * 16 + l16) * 32;
      ah[i] = *(const bf16x8*)&sAh[ra + colq];
      al[i] = *(const bf16x8*)&sAl[ra + colq];
      bh[i] = *(const bf16x8*)&sBh[rb + colq];
      bl[i] = *(const bf16x8*)&sBl[rb + colq];
    }
#pragma unroll
    for (int i = 0; i < 4; ++i)
#pragma unroll
      for (int j = 0; j < 4; ++j) {
        acc[i][j] = __builtin_amdgcn_mfma_f32_16x16x32_bf16(ah[i], bh[j], acc[i][j], 0, 0, 0);
        acc[i][j] = __builtin_amdgcn_mfma_f32_16x16x32_bf16(ah[i], bl[j], acc[i][j], 0, 0, 0);
        acc[i][j] = __builtin_amdgcn_mfma_f32_16x16x32_bf16(al[i], bh[j], acc[i][j], 0, 0, 0);
      }
  }

#pragma unroll
  for (int i = 0; i < 4; ++i) {
    const int row0 = bm * 128 + wm * 64 + i * 16 + quad * 4;
#pragma unroll
    for (int j = 0; j < 4; ++j) {
      const int col = bn * 128 + wn * 64 + j * 16 + l16;
#pragma unroll
      for (int r = 0; r < 4; ++r)
        E[(size_t)(row0 + r) * H_ + col] = acc[i][j][r];
    }
  }
}

// ---------- fp32 Gram: G[c] += E[c,:,kchunk] * E[c,:,kchunk]^T ----------
__global__ __launch_bounds__(256, 2) void k_gram(const float* __restrict__ E,
                                                 float* __restrict__ G) {
  __shared__ float Es[128][68];
  const int t = threadIdx.x;
  const int kc = blockIdx.x;   // 0..7  (K chunk of 256)
  const int cc = blockIdx.y;   // 0..63 capsule
  const int ti = t >> 4, tj = t & 15;

  float acc[8][8];
#pragma unroll
  for (int i = 0; i < 8; ++i)
#pragma unroll
    for (int j = 0; j < 8; ++j) acc[i][j] = 0.f;

  const float* Ec = E + (size_t)cc * S_ * H_ + kc * 256;
  for (int sub = 0; sub < 4; ++sub) {
    const float* Esrc = Ec + sub * 64;
    __syncthreads();
#pragma unroll
    for (int p = 0; p < 8; ++p) {
      int idx = t + p * 256;
      int s = idx >> 4, c4 = (idx & 15) * 4;
      *(float4*)&Es[s][c4] = *(const float4*)(Esrc + (size_t)s * H_ + c4);
    }
    __syncthreads();
    for (int kk = 0; kk < 64; kk += 4) {
      float4 a4[8], b4[8];
#pragma unroll
      for (int i = 0; i < 8; ++i) a4[i] = *(const float4*)&Es[ti + i * 16][kk];
#pragma unroll
      for (int j = 0; j < 8; ++j) b4[j] = *(const float4*)&Es[tj + j * 16][kk];
#pragma unroll
      for (int i = 0; i < 8; ++i)
#pragma unroll
        for (int j = 0; j < 8; ++j) {
          acc[i][j] = fmaf(a4[i].x, b4[j].x, acc[i][j]);
          acc[i][j] = fmaf(a4[i].y, b4[j].y, acc[i][j]);
          acc[i][j] = fmaf(a4[i].z, b4[j].z, acc[i][j]);
          acc[i][j] = fmaf(a4[i].w, b4[j].w, acc[i][j]);
        }
    }
  }
  float* Gc = G + (size_t)cc * S_ * S_;
#pragma unroll
  for (int i = 0; i < 8; ++i)
#pragma unroll
    for (int j = 0; j < 8; ++j)
      atomicAdd(&Gc[(ti + i * 16) * S_ + (tj + j * 16)], acc[i][j]);
}

// ---------- per-capsule routing iterations on G only ----------
__global__ void k_iter(const float* __restrict__ G, float* __restrict__ wv) {
  const int c = blockIdx.x;
  const int s = threadIdx.x;   // 128 threads
  __shared__ float dsh[128];
  __shared__ float red[128];
  const float* Gc = G + (size_t)c * S_ * S_;
  float b = 0.f;
  for (int it = 0; it < 3; ++it) {
    red[s] = b; __syncthreads();
    for (int off = 64; off > 0; off >>= 1) {
      if (s < off) red[s] = fmaxf(red[s], red[s + off]);
      __syncthreads();
    }
    float mx = red[0]; __syncthreads();
    float ev = expf(b - mx);
    red[s] = ev; __syncthreads();
    for (int off = 64; off > 0; off >>= 1) {
      if (s < off) red[s] = red[s] + red[s + off];
      __syncthreads();
    }
    float Z = red[0]; __syncthreads();
    float d = ev / Z;
    dsh[s] = d; __syncthreads();
    float y = 0.f;   // y_s = (G d)_s, read G columns (symmetric) for coalescing
#pragma unroll 8
    for (int j = 0; j < S_; ++j) y = fmaf(Gc[j * S_ + s], dsh[j], y);
    red[s] = d * y; __syncthreads();
    for (int off = 64; off > 0; off >>= 1) {
      if (s < off) red[s] = red[s] + red[s + off];
      __syncthreads();
    }
    float sq = red[0]; __syncthreads();
    float coeff = sq / (1.f + sq) / sqrtf(sq + 1e-9f);
    if (it == 2) wv[c * S_ + s] = coeff * d;
    else b += coeff * y;
  }
}

// ---------- out[c,h] = sum_s wv[c,s] * E[c,s,h] ----------
__global__ void k_out(const float* __restrict__ E, const float* __restrict__ wv,
                      float* __restrict__ out) {
  const int c = blockIdx.y;
  const int h = blockIdx.x * 256 + threadIdx.x;
  __shared__ float wsh[128];
  if (threadIdx.x < 128) wsh[threadIdx.x] = wv[c * S_ + threadIdx.x];
  __syncthreads();
  const float* Ec = E + (size_t)c * S_ * H_ + h;
  float acc = 0.f;
#pragma unroll 8
  for (int s = 0; s < S_; ++s) acc = fmaf(wsh[s], Ec[(size_t)s * H_], acc);
  out[(size_t)c * H_ + h] = acc;
}

extern "C" void kernel_launch(void* const* d_in, const int* in_sizes, int n_in,
                              void* d_out, int out_size, void* d_ws, size_t ws_size,
                              hipStream_t stream) {
  (void)in_sizes; (void)n_in; (void)out_size; (void)ws_size;
  const float* x = (const float*)d_in[0];
  const float* W = (const float*)d_in[1];
  float* out = (float*)d_out;
  char* ws = (char*)d_ws;

  unsigned short* xh  = (unsigned short*)(ws);                 // 32 MiB
  unsigned short* xl  = (unsigned short*)(ws + 33554432);      // 32 MiB
  unsigned short* Wth = (unsigned short*)(ws + 67108864);      // 8 MiB
  unsigned short* Wtl = (unsigned short*)(ws + 75497472);      // 8 MiB
  float*          E   = (float*)(ws + 83886080);               // 64 MiB
  float*          G   = (float*)(ws + 150994944);              // 4 MiB
  float*          wv  = (float*)(ws + 155189248);              // 32 KiB

  hipMemsetAsync(G, 0, (size_t)C_ * S_ * S_ * sizeof(float), stream);
  k_split_x<<<dim3(16384), 256, 0, stream>>>(x, xh, xl);
  k_split_tw<<<dim3(32, 32), 256, 0, stream>>>(W, Wth, Wtl);
  k_gemm3<<<dim3(16, 64), 256, 0, stream>>>(xh, xl, Wth, Wtl, E);
  k_gram<<<dim3(8, 64), 256, 0, stream>>>(E, G);
  k_iter<<<dim3(64), 128, 0, stream>>>(G, wv);
  k_out<<<dim3(8, 64), 256, 0, stream>>>(E, wv, out);
}

// Round 3
// 383.843 us; speedup vs baseline: 1.0933x; 1.0564x over previous
//
#include <hip/hip_runtime.h>

using bf16x8 = __attribute__((ext_vector_type(8))) __bf16;
using f32x4  = __attribute__((ext_vector_type(4))) float;

#define C_ 64
#define S_ 128
#define H_ 2048
#define M_ 8192

__device__ __forceinline__ unsigned short f2bf(float f) {
  unsigned u = __float_as_uint(f);
  u = u + 0x7fffu + ((u >> 16) & 1u);   // RNE
  return (unsigned short)(u >> 16);
}
__device__ __forceinline__ float bf2f(unsigned short h) {
  return __uint_as_float(((unsigned)h) << 16);
}

// async global->LDS, 16 B per lane; LDS dest = uniform base + lane*16
__device__ __forceinline__ void glds16(const unsigned short* g, unsigned short* l) {
  __builtin_amdgcn_global_load_lds(
      (const __attribute__((address_space(1))) void*)g,
      (__attribute__((address_space(3))) void*)l, 16, 0, 0);
}

// ---------------- split x into hi/lo bf16 ----------------
__global__ void k_split_x(const float* __restrict__ x,
                          unsigned short* __restrict__ xh,
                          unsigned short* __restrict__ xl) {
  int idx = blockIdx.x * 256 + threadIdx.x;
  float4 v = ((const float4*)x)[idx];
  float a[4] = {v.x, v.y, v.z, v.w};
  unsigned short h[4], l[4];
#pragma unroll
  for (int q = 0; q < 4; ++q) {
    h[q] = f2bf(a[q]);
    l[q] = f2bf(a[q] - bf2f(h[q]));
  }
  ((ushort4*)xh)[idx] = make_ushort4(h[0], h[1], h[2], h[3]);
  ((ushort4*)xl)[idx] = make_ushort4(l[0], l[1], l[2], l[3]);
}

// ------------- split + transpose W -> Wt[n][k] hi/lo -------------
__global__ void k_split_tw(const float* __restrict__ W,
                           unsigned short* __restrict__ Wth,
                           unsigned short* __restrict__ Wtl) {
  __shared__ float Ts[64][68];
  const int t = threadIdx.x;
  const int k0 = blockIdx.x * 64, n0 = blockIdx.y * 64;
#pragma unroll
  for (int p = 0; p < 4; ++p) {
    int idx = t + p * 256;
    int r = idx >> 4, c4 = (idx & 15) * 4;
    *(float4*)&Ts[r][c4] = *(const float4*)(W + (size_t)(k0 + r) * H_ + n0 + c4);
  }
  __syncthreads();
#pragma unroll
  for (int p = 0; p < 4; ++p) {
    int idx = t + p * 256;
    int rr = idx >> 4, cc = (idx & 15) * 4;   // rr = n-local, cc = k-local
    unsigned short h[4], l[4];
#pragma unroll
    for (int q = 0; q < 4; ++q) {
      float f = Ts[cc + q][rr];
      h[q] = f2bf(f);
      l[q] = f2bf(f - bf2f(h[q]));
    }
    size_t o = (size_t)(n0 + rr) * H_ + k0 + cc;
    *(ushort4*)(Wth + o) = make_ushort4(h[0], h[1], h[2], h[3]);
    *(ushort4*)(Wtl + o) = make_ushort4(l[0], l[1], l[2], l[3]);
  }
}

// ------- 3-term split-bf16 MFMA GEMM: E = A * Bt^T, E emitted as bf16 pair -------
// LDS: 128 rows x 32 ushorts (64 B), no padding; 16B groups XOR-swizzled by
// ((row>>1)&3) -> both glds staging and fragment reads conflict-free.
__global__ __launch_bounds__(256, 4) void k_gemm3(
    const unsigned short* __restrict__ Ah, const unsigned short* __restrict__ Al,
    const unsigned short* __restrict__ Bh, const unsigned short* __restrict__ Bl,
    unsigned short* __restrict__ Eh, unsigned short* __restrict__ El) {
  __shared__ unsigned short sAh[128 * 32], sAl[128 * 32], sBh[128 * 32], sBl[128 * 32];
  const int t = threadIdx.x;
  const int bn = blockIdx.x, bm = blockIdx.y;
  const int lane = t & 63, wid = t >> 6;
  const int wm = wid >> 1, wn = wid & 1;
  const int l16 = lane & 15, quad = lane >> 4;

  const int rl = lane >> 2;                    // row within 16-row chunk
  const int gg = (lane & 3) ^ ((rl >> 1) & 3); // swizzled global 16B-group
  const int c0 = wid * 2, c1 = wid * 2 + 1;
  const unsigned short* gAh0 = Ah + (size_t)(bm * 128 + c0 * 16 + rl) * H_ + gg * 8;
  const unsigned short* gAh1 = Ah + (size_t)(bm * 128 + c1 * 16 + rl) * H_ + gg * 8;
  const unsigned short* gAl0 = Al + (size_t)(bm * 128 + c0 * 16 + rl) * H_ + gg * 8;
  const unsigned short* gAl1 = Al + (size_t)(bm * 128 + c1 * 16 + rl) * H_ + gg * 8;
  const unsigned short* gBh0 = Bh + (size_t)(bn * 128 + c0 * 16 + rl) * H_ + gg * 8;
  const unsigned short* gBh1 = Bh + (size_t)(bn * 128 + c1 * 16 + rl) * H_ + gg * 8;
  const unsigned short* gBl0 = Bl + (size_t)(bn * 128 + c0 * 16 + rl) * H_ + gg * 8;
  const unsigned short* gBl1 = Bl + (size_t)(bn * 128 + c1 * 16 + rl) * H_ + gg * 8;
  unsigned short* lA0 = sAh + c0 * 512;  // chunk = 16 rows * 32 ushorts = 1 KiB
  unsigned short* lA1 = sAh + c1 * 512;
  unsigned short* lAl0 = sAl + c0 * 512;
  unsigned short* lAl1 = sAl + c1 * 512;
  unsigned short* lB0 = sBh + c0 * 512;
  unsigned short* lB1 = sBh + c1 * 512;
  unsigned short* lBl0 = sBl + c0 * 512;
  unsigned short* lBl1 = sBl + c1 * 512;

  const int swz = ((l16 >> 1) & 3);
  const int colq = ((quad ^ swz) * 8);

  f32x4 acc[4][4];
#pragma unroll
  for (int i = 0; i < 4; ++i)
#pragma unroll
    for (int j = 0; j < 4; ++j) acc[i][j] = (f32x4)0.f;

  for (int k0 = 0; k0 < H_; k0 += 32) {
    __syncthreads();
    glds16(gAh0 + k0, lA0);
    glds16(gAh1 + k0, lA1);
    glds16(gAl0 + k0, lAl0);
    glds16(gAl1 + k0, lAl1);
    glds16(gBh0 + k0, lB0);
    glds16(gBh1 + k0, lB1);
    glds16(gBl0 + k0, lBl0);
    glds16(gBl1 + k0, lBl1);
    __syncthreads();

    bf16x8 ah[4], al[4], bh[4], bl[4];
#pragma unroll
    for (int i = 0; i < 4; ++i) {
      const int ra = (wm * 64 + i * 16 + l16) * 32;
      const int rb = (wn * 64 + i * 16 + l16) * 32;
      ah[i] = *(const bf16x8*)&sAh[ra + colq];
      al[i] = *(const bf16x8*)&sAl[ra + colq];
      bh[i] = *(const bf16x8*)&sBh[rb + colq];
      bl[i] = *(const bf16x8*)&sBl[rb + colq];
    }
#pragma unroll
    for (int i = 0; i < 4; ++i)
#pragma unroll
      for (int j = 0; j < 4; ++j) {
        acc[i][j] = __builtin_amdgcn_mfma_f32_16x16x32_bf16(ah[i], bh[j], acc[i][j], 0, 0, 0);
        acc[i][j] = __builtin_amdgcn_mfma_f32_16x16x32_bf16(ah[i], bl[j], acc[i][j], 0, 0, 0);
        acc[i][j] = __builtin_amdgcn_mfma_f32_16x16x32_bf16(al[i], bh[j], acc[i][j], 0, 0, 0);
      }
  }

#pragma unroll
  for (int i = 0; i < 4; ++i) {
    const int row0 = bm * 128 + wm * 64 + i * 16 + quad * 4;
#pragma unroll
    for (int j = 0; j < 4; ++j) {
      const int col = bn * 128 + wn * 64 + j * 16 + l16;
#pragma unroll
      for (int r = 0; r < 4; ++r) {
        float v = acc[i][j][r];
        unsigned short hh = f2bf(v);
        unsigned short ll = f2bf(v - bf2f(hh));
        Eh[(size_t)(row0 + r) * H_ + col] = hh;
        El[(size_t)(row0 + r) * H_ + col] = ll;
      }
    }
  }
}

// ---- MFMA Gram: G[c] += Eh*Eh^T + Eh*El^T + El*Eh^T over a 256-wide K chunk ----
__global__ __launch_bounds__(256, 4) void k_gram_mfma(
    const unsigned short* __restrict__ Eh, const unsigned short* __restrict__ El,
    float* __restrict__ G) {
  __shared__ unsigned short sH[128 * 32], sL[128 * 32];
  const int t = threadIdx.x;
  const int kc = blockIdx.x;   // 0..7, K chunk of 256
  const int cc = blockIdx.y;   // capsule
  const int lane = t & 63, wid = t >> 6;
  const int wm = wid >> 1, wn = wid & 1;
  const int l16 = lane & 15, quad = lane >> 4;

  const int rl = lane >> 2;
  const int gg = (lane & 3) ^ ((rl >> 1) & 3);
  const int c0 = wid * 2, c1 = c0 + 1;
  const size_t kbase = (size_t)kc * 256 + gg * 8;
  const unsigned short* gH0 = Eh + (size_t)(cc * 128 + c0 * 16 + rl) * H_ + kbase;
  const unsigned short* gH1 = Eh + (size_t)(cc * 128 + c1 * 16 + rl) * H_ + kbase;
  const unsigned short* gL0 = El + (size_t)(cc * 128 + c0 * 16 + rl) * H_ + kbase;
  const unsigned short* gL1 = El + (size_t)(cc * 128 + c1 * 16 + rl) * H_ + kbase;
  unsigned short* lH0 = sH + c0 * 512;
  unsigned short* lH1 = sH + c1 * 512;
  unsigned short* lL0 = sL + c0 * 512;
  unsigned short* lL1 = sL + c1 * 512;

  const int swz = ((l16 >> 1) & 3);
  const int colq = ((quad ^ swz) * 8);

  f32x4 acc[4][4];
#pragma unroll
  for (int i = 0; i < 4; ++i)
#pragma unroll
    for (int j = 0; j < 4; ++j) acc[i][j] = (f32x4)0.f;

  for (int k0 = 0; k0 < 256; k0 += 32) {
    __syncthreads();
    glds16(gH0 + k0, lH0);
    glds16(gH1 + k0, lH1);
    glds16(gL0 + k0, lL0);
    glds16(gL1 + k0, lL1);
    __syncthreads();

    bf16x8 ah[4], al[4], bh[4], bl[4];
#pragma unroll
    for (int i = 0; i < 4; ++i) {
      const int ra = (wm * 64 + i * 16 + l16) * 32;
      const int rb = (wn * 64 + i * 16 + l16) * 32;
      ah[i] = *(const bf16x8*)&sH[ra + colq];
      al[i] = *(const bf16x8*)&sL[ra + colq];
      bh[i] = *(const bf16x8*)&sH[rb + colq];
      bl[i] = *(const bf16x8*)&sL[rb + colq];
    }
#pragma unroll
    for (int i = 0; i < 4; ++i)
#pragma unroll
      for (int j = 0; j < 4; ++j) {
        acc[i][j] = __builtin_amdgcn_mfma_f32_16x16x32_bf16(ah[i], bh[j], acc[i][j], 0, 0, 0);
        acc[i][j] = __builtin_amdgcn_mfma_f32_16x16x32_bf16(ah[i], bl[j], acc[i][j], 0, 0, 0);
        acc[i][j] = __builtin_amdgcn_mfma_f32_16x16x32_bf16(al[i], bh[j], acc[i][j], 0, 0, 0);
      }
  }

  float* Gc = G + (size_t)cc * S_ * S_;
#pragma unroll
  for (int i = 0; i < 4; ++i) {
    const int row0 = wm * 64 + i * 16 + quad * 4;
#pragma unroll
    for (int j = 0; j < 4; ++j) {
      const int col = wn * 64 + j * 16 + l16;
#pragma unroll
      for (int r = 0; r < 4; ++r)
        atomicAdd(&Gc[(row0 + r) * S_ + col], acc[i][j][r]);
    }
  }
}

// ---------- per-capsule routing iterations on G only ----------
__global__ void k_iter(const float* __restrict__ G, float* __restrict__ wv) {
  const int c = blockIdx.x;
  const int s = threadIdx.x;   // 128 threads
  __shared__ float dsh[128];
  __shared__ float red[128];
  const float* Gc = G + (size_t)c * S_ * S_;
  float b = 0.f;
  for (int it = 0; it < 3; ++it) {
    red[s] = b; __syncthreads();
    for (int off = 64; off > 0; off >>= 1) {
      if (s < off) red[s] = fmaxf(red[s], red[s + off]);
      __syncthreads();
    }
    float mx = red[0]; __syncthreads();
    float ev = expf(b - mx);
    red[s] = ev; __syncthreads();
    for (int off = 64; off > 0; off >>= 1) {
      if (s < off) red[s] = red[s] + red[s + off];
      __syncthreads();
    }
    float Z = red[0]; __syncthreads();
    float d = ev / Z;
    dsh[s] = d; __syncthreads();
    float y = 0.f;
#pragma unroll 8
    for (int j = 0; j < S_; ++j) y = fmaf(Gc[j * S_ + s], dsh[j], y);
    red[s] = d * y; __syncthreads();
    for (int off = 64; off > 0; off >>= 1) {
      if (s < off) red[s] = red[s] + red[s + off];
      __syncthreads();
    }
    float sq = red[0]; __syncthreads();
    float coeff = sq / (1.f + sq) / sqrtf(sq + 1e-9f);
    if (it == 2) wv[c * S_ + s] = coeff * d;
    else b += coeff * y;
  }
}

// ---------- out[c,h] = sum_s wv[c,s] * (Eh+El)[c,s,h] ----------
__global__ void k_out(const unsigned short* __restrict__ Eh,
                      const unsigned short* __restrict__ El,
                      const float* __restrict__ wv, float* __restrict__ out) {
  const int c = blockIdx.y;
  const int h = blockIdx.x * 256 + threadIdx.x;
  __shared__ float wsh[128];
  if (threadIdx.x < 128) wsh[threadIdx.x] = wv[c * S_ + threadIdx.x];
  __syncthreads();
  const unsigned short* Ph = Eh + (size_t)c * S_ * H_ + h;
  const unsigned short* Pl = El + (size_t)c * S_ * H_ + h;
  float acc = 0.f;
#pragma unroll 8
  for (int s = 0; s < S_; ++s)
    acc = fmaf(wsh[s], bf2f(Ph[(size_t)s * H_]) + bf2f(Pl[(size_t)s * H_]), acc);
  out[(size_t)c * H_ + h] = acc;
}

extern "C" void kernel_launch(void* const* d_in, const int* in_sizes, int n_in,
                              void* d_out, int out_size, void* d_ws, size_t ws_size,
                              hipStream_t stream) {
  (void)in_sizes; (void)n_in; (void)out_size; (void)ws_size;
  const float* x = (const float*)d_in[0];
  const float* W = (const float*)d_in[1];
  float* out = (float*)d_out;
  char* ws = (char*)d_ws;

  unsigned short* xh  = (unsigned short*)(ws);                 // 32 MiB
  unsigned short* xl  = (unsigned short*)(ws + 33554432);      // 32 MiB
  unsigned short* Wth = (unsigned short*)(ws + 67108864);      // 8 MiB
  unsigned short* Wtl = (unsigned short*)(ws + 75497472);      // 8 MiB
  unsigned short* Eh  = (unsigned short*)(ws + 83886080);      // 32 MiB
  unsigned short* El  = (unsigned short*)(ws + 117440512);     // 32 MiB
  float*          G   = (float*)(ws + 150994944);              // 4 MiB
  float*          wv  = (float*)(ws + 155189248);              // 32 KiB

  hipMemsetAsync(G, 0, (size_t)C_ * S_ * S_ * sizeof(float), stream);
  k_split_x<<<dim3(16384), 256, 0, stream>>>(x, xh, xl);
  k_split_tw<<<dim3(32, 32), 256, 0, stream>>>(W, Wth, Wtl);
  k_gemm3<<<dim3(16, 64), 256, 0, stream>>>(xh, xl, Wth, Wtl, Eh, El);
  k_gram_mfma<<<dim3(8, 64), 256, 0, stream>>>(Eh, El, G);
  k_iter<<<dim3(64), 128, 0, stream>>>(G, wv);
  k_out<<<dim3(8, 64), 256, 0, stream>>>(Eh, El, wv, out);
}